// Round 3
// baseline (74.169 us; speedup 1.0000x reference)
//
#include <hip/hip_runtime.h>

// Problem constants (fixed by the reference):
constexpr int BATCH = 256;
constexpr int CH    = 512;
constexpr int KS    = 5;
constexpr int PAD   = (KS - 1) / 2;  // 'same' padding = 2
constexpr float LOG2E = 1.4426950408889634f;

// Fully fused: conv + stats + rank-1 softmax attention in ONE launch.
// One block per batch (grid 256 = #CUs), 1024 threads = 4 waves/SIMD.
//
// Hot-loop economics per CU (= per batch, 512x512 = 262144 exps):
//   - trans pipe floor: 1024 exp wave-ops/SIMD x 8 cyc = 8192 cyc ~ 3.4 us.
//   - 8 c-rows per thread: one kh4/vh4 LDS broadcast pair feeds 32 exps
//     -> 256 ds_read_b128 per batch (~3k cyc) - LDS pipe far off the floor.
//   - VALU: 3 ops/exp (arg-fma, den-add, num-fma) ~ 6144 cyc, overlaps trans.
//   - log2e folded into qh at conv time -> raw v_exp_f32 (exp2), no mul.
// d-range split 16 ways (g = t>>6, 32 d each) for full occupancy; partials
// combine through a 64 KB LDS buffer (2-way bank aliasing only = free).
__global__ __launch_bounds__(1024, 1) void fused_attn1d_kernel(
    const float* __restrict__ q, const float* __restrict__ k, const float* __restrict__ v,
    const float* __restrict__ wq, const float* __restrict__ wk, const float* __restrict__ wv,
    float* __restrict__ out)
{
    __shared__ __align__(16) float sq[CH], sk[CH], sv[CH];
    __shared__ __align__(16) float qh2[CH], kh[CH], vh[CH];
    __shared__ float2 red[16][CH];         // per-d-group partial {num, den}, 64 KB
    __shared__ float wred_max[8], wred_min[8];

    const int b = blockIdx.x;
    const int t = threadIdx.x;

    // ---- stage raw rows (threads 0..511, coalesced dword) ----
    if (t < CH) {
        sq[t] = q[b * CH + t];
        sk[t] = k[b * CH + t];
        sv[t] = v[b * CH + t];
    }
    __syncthreads();

    // ---- conv ('same' cross-correlation, zero-pad) + per-wave k-stats ----
    if (t < CH) {
        float w_q[KS], w_k[KS], w_v[KS];
#pragma unroll
        for (int j = 0; j < KS; ++j) { w_q[j] = wq[j]; w_k[j] = wk[j]; w_v[j] = wv[j]; }

        float aq = 0.f, ak = 0.f, av = 0.f;
#pragma unroll
        for (int j = 0; j < KS; ++j) {
            const int idx = t + j - PAD;
            if (idx >= 0 && idx < CH) {
                aq = fmaf(sq[idx], w_q[j], aq);
                ak = fmaf(sk[idx], w_k[j], ak);
                av = fmaf(sv[idx], w_v[j], av);
            }
        }
        qh2[t] = aq * LOG2E;   // pre-scale so hot loop uses raw exp2
        kh[t]  = ak;
        vh[t]  = av;

        // wave-level max/min of kh; leaders publish to LDS (no serial combine)
        float lmax = ak, lmin = ak;
#pragma unroll
        for (int off = 32; off > 0; off >>= 1) {
            lmax = fmaxf(lmax, __shfl_down(lmax, off, 64));
            lmin = fminf(lmin, __shfl_down(lmin, off, 64));
        }
        if ((t & 63) == 0) { wred_max[t >> 6] = lmax; wred_min[t >> 6] = lmin; }
    }
    __syncthreads();

    // Every thread folds the 8 wave partials locally: 8 fmax + 8 fmin,
    // no t==0 serialization, no extra barrier.
    float kmax = wred_max[0], kmin = wred_min[0];
#pragma unroll
    for (int i = 1; i < 8; ++i) {
        kmax = fmaxf(kmax, wred_max[i]);
        kmin = fminf(kmin, wred_min[i]);
    }

    // ---- rank-1 attention: g = d-group (16 x 32 d), li covers 8 c-rows ----
    const int g  = t >> 6;          // 0..15
    const int li = t & 63;          // c rows: li + 64*r, r = 0..7

    float qr[8], nm2[8], den[8], num[8];
#pragma unroll
    for (int r = 0; r < 8; ++r) {
        const float qc2 = qh2[li + 64 * r];
        qr[r]  = qc2;
        // exact row max of qc*kh[d] in log2 domain (sign-selected extreme)
        nm2[r] = -((qc2 >= 0.f) ? qc2 * kmax : qc2 * kmin);
        den[r] = 0.f;
        num[r] = 0.f;
    }

    const float4* kh4 = (const float4*)kh;
    const float4* vh4 = (const float4*)vh;
    const int base = g * 8;         // 8 float4 chunks = 32 d per group
#pragma unroll 4
    for (int i = 0; i < 8; ++i) {
        const float4 kk = kh4[base + i];   // wave-uniform LDS broadcast
        const float4 vv = vh4[base + i];
#pragma unroll
        for (int r = 0; r < 8; ++r) {
            const float e0 = __builtin_amdgcn_exp2f(fmaf(qr[r], kk.x, nm2[r]));
            const float e1 = __builtin_amdgcn_exp2f(fmaf(qr[r], kk.y, nm2[r]));
            const float e2 = __builtin_amdgcn_exp2f(fmaf(qr[r], kk.z, nm2[r]));
            const float e3 = __builtin_amdgcn_exp2f(fmaf(qr[r], kk.w, nm2[r]));
            den[r] += (e0 + e1) + (e2 + e3);
            num[r] = fmaf(e0, vv.x, num[r]);
            num[r] = fmaf(e1, vv.y, num[r]);
            num[r] = fmaf(e2, vv.z, num[r]);
            num[r] = fmaf(e3, vv.w, num[r]);
        }
    }
#pragma unroll
    for (int r = 0; r < 8; ++r) red[g][li + 64 * r] = make_float2(num[r], den[r]);
    __syncthreads();

    // ---- combine the 16 d-group partials, write out ----
    if (t < CH) {
        float n = 0.f, d = 0.f;
#pragma unroll
        for (int g2 = 0; g2 < 16; ++g2) {
            const float2 p = red[g2][t];
            n += p.x; d += p.y;
        }
        out[b * CH + t] = n / d;
    }
}

extern "C" void kernel_launch(void* const* d_in, const int* in_sizes, int n_in,
                              void* d_out, int out_size, void* d_ws, size_t ws_size,
                              hipStream_t stream) {
    const float* q  = (const float*)d_in[0];
    const float* k  = (const float*)d_in[1];
    const float* v  = (const float*)d_in[2];
    const float* wq = (const float*)d_in[3];
    const float* wk = (const float*)d_in[4];
    const float* wv = (const float*)d_in[5];
    float* out = (float*)d_out;
    (void)d_ws; (void)ws_size;

    fused_attn1d_kernel<<<BATCH, 1024, 0, stream>>>(q, k, v, wq, wk, wv, out);
}

// Round 4
// 73.312 us; speedup vs baseline: 1.0117x; 1.0117x over previous
//
#include <hip/hip_runtime.h>

// Problem constants (fixed by the reference):
constexpr int BATCH = 256;
constexpr int CH    = 512;
constexpr int KS    = 5;
constexpr int PAD   = (KS - 1) / 2;  // 'same' padding = 2
constexpr float LOG2E = 1.4426950408889634f;

// Fully fused: conv + stats + rank-1 softmax attention, ONE launch.
// One block per batch (grid 256 = #CUs), 1024 threads = 4 waves/SIMD.
//
// Round-2 hot-loop structure (measured best: 73.0 us) + prologue trims:
//   - conv split across the block: waves 0-7 conv k + stats shuffle,
//     waves 8-15 conv q and v concurrently -> stats chain overlapped.
//   - no serial t==0 stats combine, no third barrier: leaders publish 8
//     wave extrema, every thread folds 8 entries locally.
// Hot loop per CU (= per batch, 262144 exps):
//   - trans floor: 1024 exp wave-ops/SIMD x 8 cyc = 8192 cyc ~ 3.4 us
//   - 4 c-rows/thread: one kh4/vh4 broadcast pair feeds 16 exps
//   - log2e folded into qh -> raw v_exp_f32, 3 VALU/exp overlapped.
__global__ __launch_bounds__(1024, 1) void fused_attn1d_kernel(
    const float* __restrict__ q, const float* __restrict__ k, const float* __restrict__ v,
    const float* __restrict__ wq, const float* __restrict__ wk, const float* __restrict__ wv,
    float* __restrict__ out)
{
    __shared__ __align__(16) float sq[CH], sk[CH], sv[CH];
    __shared__ __align__(16) float qh2[CH], kh[CH], vh[CH];
    __shared__ float2 red[8][CH];          // per-d-group partial {num, den}, 32 KB
    __shared__ float wred_max[8], wred_min[8];

    const int b = blockIdx.x;
    const int t = threadIdx.x;
    const int lo = t;                      // lower-half channel index
    const int up = t - CH;                 // upper-half channel index

    // ---- stage raw rows: lower half loads k+v, upper half loads q ----
    if (t < CH) {
        sk[lo] = k[b * CH + lo];
        sv[lo] = v[b * CH + lo];
    } else {
        sq[up] = q[b * CH + up];
    }
    __syncthreads();

    // ---- conv ('same' cross-correlation, zero-pad), split across halves ----
    if (t < CH) {
        // k-conv + wave stats (the serial shuffle chain overlaps the upper
        // half's q/v convs).
        float w_k[KS];
#pragma unroll
        for (int j = 0; j < KS; ++j) w_k[j] = wk[j];
        float ak = 0.f;
#pragma unroll
        for (int j = 0; j < KS; ++j) {
            const int idx = lo + j - PAD;
            if (idx >= 0 && idx < CH) ak = fmaf(sk[idx], w_k[j], ak);
        }
        kh[lo] = ak;

        float lmax = ak, lmin = ak;
#pragma unroll
        for (int off = 32; off > 0; off >>= 1) {
            lmax = fmaxf(lmax, __shfl_down(lmax, off, 64));
            lmin = fminf(lmin, __shfl_down(lmin, off, 64));
        }
        if ((t & 63) == 0) { wred_max[t >> 6] = lmax; wred_min[t >> 6] = lmin; }
    } else {
        // q-conv and v-conv on the upper half.
        float w_q[KS], w_v[KS];
#pragma unroll
        for (int j = 0; j < KS; ++j) { w_q[j] = wq[j]; w_v[j] = wv[j]; }
        float aq = 0.f, av = 0.f;
#pragma unroll
        for (int j = 0; j < KS; ++j) {
            const int idx = up + j - PAD;
            if (idx >= 0 && idx < CH) {
                aq = fmaf(sq[idx], w_q[j], aq);
                av = fmaf(sv[idx], w_v[j], av);
            }
        }
        qh2[up] = aq * LOG2E;   // pre-scale so hot loop uses raw exp2
        vh[up]  = av;
    }
    __syncthreads();

    // Every thread folds the 8 wave extrema locally (LDS broadcast, free).
    float kmax = wred_max[0], kmin = wred_min[0];
#pragma unroll
    for (int i = 1; i < 8; ++i) {
        kmax = fmaxf(kmax, wred_max[i]);
        kmin = fminf(kmin, wred_min[i]);
    }

    // ---- rank-1 attention: g = d-group (8 x 64 d), li covers 4 c-rows ----
    const int g  = t >> 7;          // 0..7
    const int li = t & 127;         // c rows: li + 128*r, r = 0..3

    float qr[4], nm2[4], den[4], num[4];
#pragma unroll
    for (int r = 0; r < 4; ++r) {
        const float qc2 = qh2[li + 128 * r];
        qr[r]  = qc2;
        // exact row max of qc*kh[d] in log2 domain (sign-selected extreme)
        nm2[r] = -((qc2 >= 0.f) ? qc2 * kmax : qc2 * kmin);
        den[r] = 0.f;
        num[r] = 0.f;
    }

    const float4* kh4 = (const float4*)kh;
    const float4* vh4 = (const float4*)vh;
    const int base = g * 16;        // 16 float4 chunks = 64 d per group
#pragma unroll 4
    for (int i = 0; i < 16; ++i) {
        const float4 kk = kh4[base + i];   // wave-uniform LDS broadcast
        const float4 vv = vh4[base + i];
#pragma unroll
        for (int r = 0; r < 4; ++r) {
            const float e0 = __builtin_amdgcn_exp2f(fmaf(qr[r], kk.x, nm2[r]));
            const float e1 = __builtin_amdgcn_exp2f(fmaf(qr[r], kk.y, nm2[r]));
            const float e2 = __builtin_amdgcn_exp2f(fmaf(qr[r], kk.z, nm2[r]));
            const float e3 = __builtin_amdgcn_exp2f(fmaf(qr[r], kk.w, nm2[r]));
            den[r] += (e0 + e1) + (e2 + e3);
            num[r] = fmaf(e0, vv.x, num[r]);
            num[r] = fmaf(e1, vv.y, num[r]);
            num[r] = fmaf(e2, vv.z, num[r]);
            num[r] = fmaf(e3, vv.w, num[r]);
        }
    }
#pragma unroll
    for (int r = 0; r < 4; ++r) red[g][li + 128 * r] = make_float2(num[r], den[r]);
    __syncthreads();

    // ---- combine the 8 d-group partials, write out ----
    if (t < CH) {
        float n = 0.f, d = 0.f;
#pragma unroll
        for (int g2 = 0; g2 < 8; ++g2) {
            const float2 p = red[g2][t];
            n += p.x; d += p.y;
        }
        out[b * CH + t] = n / d;
    }
}

extern "C" void kernel_launch(void* const* d_in, const int* in_sizes, int n_in,
                              void* d_out, int out_size, void* d_ws, size_t ws_size,
                              hipStream_t stream) {
    const float* q  = (const float*)d_in[0];
    const float* k  = (const float*)d_in[1];
    const float* v  = (const float*)d_in[2];
    const float* wq = (const float*)d_in[3];
    const float* wk = (const float*)d_in[4];
    const float* wv = (const float*)d_in[5];
    float* out = (float*)d_out;
    (void)d_ws; (void)ws_size;

    fused_attn1d_kernel<<<BATCH, 1024, 0, stream>>>(q, k, v, wq, wk, wv, out);
}